// Round 1
// baseline (5102.563 us; speedup 1.0000x reference)
//
#include <hip/hip_runtime.h>

constexpr float LN_EPS = 1e-5f;

__device__ inline float hsum4(float4 v){ return v.x+v.y+v.z+v.w; }
__device__ inline float hdot4(float4 v){ return v.x*v.x+v.y*v.y+v.z*v.z+v.w*v.w; }
__device__ inline float4 f4add(float4 a, float4 b){ return make_float4(a.x+b.x,a.y+b.y,a.z+b.z,a.w+b.w); }
__device__ inline float4 lnrelu(float4 y, float mean, float rs, float4 g, float4 b){
  float4 o;
  o.x = fmaxf(fmaf((y.x-mean)*rs, g.x, b.x), 0.f);
  o.y = fmaxf(fmaf((y.y-mean)*rs, g.y, b.y), 0.f);
  o.z = fmaxf(fmaf((y.z-mean)*rs, g.z, b.z), 0.f);
  o.w = fmaxf(fmaf((y.w-mean)*rs, g.w, b.w), 0.f);
  return o;
}

// ---------------- input LayerNorm ----------------
__global__ __launch_bounds__(256) void input_ln_k(
    const float* __restrict__ h, const float* __restrict__ g,
    const float* __restrict__ b, float* __restrict__ out, int N){
  int w = blockIdx.x*(blockDim.x>>6) + (threadIdx.x>>6);
  if (w >= N) return;
  int lane = threadIdx.x & 63;
  float2 v = *(const float2*)(h + (long)w*128 + lane*2);
  float s = v.x+v.y, sq = v.x*v.x + v.y*v.y;
  #pragma unroll
  for (int x=1;x<64;x<<=1){ s += __shfl_xor(s,x); sq += __shfl_xor(sq,x); }
  float mean = s*(1.f/128.f), var = sq*(1.f/128.f) - mean*mean;
  float rs = rsqrtf(var + LN_EPS);
  float2 gv = *(const float2*)(g + lane*2), bv = *(const float2*)(b + lane*2);
  float2 o;
  o.x = fmaf((v.x-mean)*rs, gv.x, bv.x);
  o.y = fmaf((v.y-mean)*rs, gv.y, bv.y);
  *(float2*)(out + (long)w*128 + lane*2) = o;
}

// ---------------- edge scatter-add (GIN aggregation) ----------------
__global__ __launch_bounds__(256) void scatter_edges(
    const float* __restrict__ h, const int* __restrict__ src,
    const int* __restrict__ dst, float* __restrict__ agg, int E){
  long t = (long)blockIdx.x*blockDim.x + threadIdx.x;
  long e = t >> 7;
  if (e >= E) return;
  int c = (int)(t & 127);
  int s = src[e], d = dst[e];
  float v = h[(long)s*128 + c];
  atomicAdd(agg + (long)d*128 + c, v);
}

// ---------------- fused GEMM + bias + LN(+LN) + ReLU (+residual) ----------------
// MODE 0: z = A + A2;  out = relu(LN1(z@W + bias))
// MODE 1: z = A;       t = relu(LN1(z@W + bias)); u = relu(LN2(t)); out = u (+ resid)
// Row-parallel: each block owns 128 rows; in-place out over A/A2 is safe.
template<int MODE>
__global__ __launch_bounds__(256, 2) void gemm_fused(
    const float* __restrict__ A, const float* __restrict__ A2,
    const float* __restrict__ W, const float* __restrict__ bias,
    const float* __restrict__ g1v, const float* __restrict__ b1v,
    const float* __restrict__ g2v, const float* __restrict__ b2v,
    const float* __restrict__ resid,
    float* __restrict__ out, int N){
  __shared__ float Wlds[128][128];   // 64 KB -> 2 blocks/CU
  const int tid = threadIdx.x;
  {
    const float4* Wg = (const float4*)W;
    float4* Wl = (float4*)&Wlds[0][0];
    #pragma unroll
    for (int i=0;i<16;i++) Wl[i*256 + tid] = Wg[i*256 + tid];
  }
  __syncthreads();

  const int wid = tid >> 6, lane = tid & 63;
  const int rg = lane >> 4, cg = lane & 15;
  const int c0 = cg*4, c1 = 64 + cg*4;
  const long rbase = (long)blockIdx.x*128 + wid*32 + rg*8;

  int off[8];
  #pragma unroll
  for (int m=0;m<8;m++){
    long r = rbase + m; if (r > (long)N-1) r = N-1;   // clamp tail rows
    off[m] = (int)(r * 128);
  }

  float4 acc[8], acc2[8];
  #pragma unroll
  for (int m=0;m<8;m++){ acc[m]=make_float4(0,0,0,0); acc2[m]=make_float4(0,0,0,0); }

  float4 zA[8], zB[8];

  auto loadc = [&](int k0, float4* zc){
    #pragma unroll
    for (int m=0;m<8;m++){
      float4 v = *(const float4*)(A + off[m] + k0);
      if (MODE==0){
        float4 v2 = *(const float4*)(A2 + off[m] + k0);
        v.x+=v2.x; v.y+=v2.y; v.z+=v2.z; v.w+=v2.w;
      }
      zc[m]=v;
    }
  };
  auto comp = [&](int k0, const float4* zc){
    #pragma unroll
    for (int kk=0;kk<4;kk++){
      const float4 w0 = *(const float4*)&Wlds[k0+kk][c0];
      const float4 w1 = *(const float4*)&Wlds[k0+kk][c1];
      #pragma unroll
      for (int m=0;m<8;m++){
        float zv = (kk==0)?zc[m].x:(kk==1)?zc[m].y:(kk==2)?zc[m].z:zc[m].w;
        acc[m].x  = fmaf(zv, w0.x, acc[m].x);
        acc[m].y  = fmaf(zv, w0.y, acc[m].y);
        acc[m].z  = fmaf(zv, w0.z, acc[m].z);
        acc[m].w  = fmaf(zv, w0.w, acc[m].w);
        acc2[m].x = fmaf(zv, w1.x, acc2[m].x);
        acc2[m].y = fmaf(zv, w1.y, acc2[m].y);
        acc2[m].z = fmaf(zv, w1.z, acc2[m].z);
        acc2[m].w = fmaf(zv, w1.w, acc2[m].w);
      }
    }
  };

  loadc(0, zA);
  #pragma unroll 1
  for (int kc=0; kc<32; kc+=2){
    loadc((kc+1)*4, zB);          // kc+1 <= 31
    comp(kc*4, zA);
    if (kc+2 < 32) loadc((kc+2)*4, zA);
    comp((kc+1)*4, zB);
  }

  // ---- epilogue ----
  const float4 bi0 = *(const float4*)(bias + c0), bi1 = *(const float4*)(bias + c1);
  const float4 g10 = *(const float4*)(g1v + c0), g11 = *(const float4*)(g1v + c1);
  const float4 b10 = *(const float4*)(b1v + c0), b11 = *(const float4*)(b1v + c1);
  float4 g20, g21, b20, b21;
  if (MODE==1){
    g20 = *(const float4*)(g2v + c0); g21 = *(const float4*)(g2v + c1);
    b20 = *(const float4*)(b2v + c0); b21 = *(const float4*)(b2v + c1);
  }

  #pragma unroll
  for (int m=0;m<8;m++){
    long r = rbase + m;
    float4 y0 = f4add(acc[m], bi0);
    float4 y1 = f4add(acc2[m], bi1);
    float s = hsum4(y0)+hsum4(y1);
    float sq = hdot4(y0)+hdot4(y1);
    #pragma unroll
    for (int x=1;x<16;x<<=1){ s += __shfl_xor(s,x); sq += __shfl_xor(sq,x); }
    float mean = s*(1.f/128.f);
    float var  = sq*(1.f/128.f) - mean*mean;
    float rs = rsqrtf(var + LN_EPS);
    float4 t0 = lnrelu(y0, mean, rs, g10, b10);
    float4 t1 = lnrelu(y1, mean, rs, g11, b11);
    if (MODE==1){
      float s2 = hsum4(t0)+hsum4(t1);
      float sq2 = hdot4(t0)+hdot4(t1);
      #pragma unroll
      for (int x=1;x<16;x<<=1){ s2 += __shfl_xor(s2,x); sq2 += __shfl_xor(sq2,x); }
      float mean2 = s2*(1.f/128.f);
      float var2  = sq2*(1.f/128.f) - mean2*mean2;
      float rs2 = rsqrtf(var2 + LN_EPS);
      t0 = lnrelu(t0, mean2, rs2, g20, b20);
      t1 = lnrelu(t1, mean2, rs2, g21, b21);
      if (resid){
        float4 r0 = *(const float4*)(resid + off[m] + c0);
        float4 r1 = *(const float4*)(resid + off[m] + c1);
        t0 = f4add(t0, r0); t1 = f4add(t1, r1);
      }
    }
    if (r < (long)N){
      *(float4*)(out + off[m] + c0) = t0;
      *(float4*)(out + off[m] + c1) = t1;
    }
  }
}

// ---------------- pooling over sorted graph_ids ----------------
__global__ __launch_bounds__(256) void pool_k(
    const float* __restrict__ h, const int* __restrict__ gids,
    float* __restrict__ sums, float* __restrict__ counts, int N){
  const int CHUNK = 256;
  int w = blockIdx.x*(blockDim.x>>6) + (threadIdx.x>>6);
  int lane = threadIdx.x & 63;
  int n0 = w*CHUNK; if (n0 >= N) return;
  int n1 = min(n0+CHUNK, N);
  float2 acc = make_float2(0.f,0.f); float cnt = 0.f;
  int gprev = gids[n0];
  for (int n=n0; n<n1; ++n){
    int g = gids[n];
    if (g != gprev){
      atomicAdd(sums + (long)gprev*128 + lane*2,     acc.x);
      atomicAdd(sums + (long)gprev*128 + lane*2 + 1, acc.y);
      if (lane==0) atomicAdd(counts + gprev, cnt);
      acc = make_float2(0.f,0.f); cnt = 0.f; gprev = g;
    }
    float2 v = *(const float2*)(h + (long)n*128 + lane*2);
    acc.x += v.x; acc.y += v.y; cnt += 1.f;
  }
  atomicAdd(sums + (long)gprev*128 + lane*2,     acc.x);
  atomicAdd(sums + (long)gprev*128 + lane*2 + 1, acc.y);
  if (lane==0) atomicAdd(counts + gprev, cnt);
}

__global__ __launch_bounds__(256) void norm_k(
    const float* __restrict__ sums, const float* __restrict__ counts,
    float* __restrict__ out, int GD){
  int i = blockIdx.x*blockDim.x + threadIdx.x;
  if (i >= GD) return;
  float c = counts[i>>7];
  out[i] = sums[i] / fmaxf(c, 1.0f);
}

extern "C" void kernel_launch(void* const* d_in, const int* in_sizes, int n_in,
                              void* d_out, int out_size, void* d_ws, size_t ws_size,
                              hipStream_t stream) {
  const float* h_in  = (const float*)d_in[0];
  const int*   src   = (const int*)d_in[1];
  const int*   dst   = (const int*)d_in[2];
  const int*   gids  = (const int*)d_in[3];
  const float* ilng  = (const float*)d_in[4];
  const float* ilnb  = (const float*)d_in[5];
  const float* W1    = (const float*)d_in[6];
  const float* b1    = (const float*)d_in[7];
  const float* ln1g  = (const float*)d_in[8];
  const float* ln1b  = (const float*)d_in[9];
  const float* W2    = (const float*)d_in[10];
  const float* b2    = (const float*)d_in[11];
  const float* ln2g  = (const float*)d_in[12];
  const float* ln2b  = (const float*)d_in[13];
  const float* ng    = (const float*)d_in[14];
  const float* nb    = (const float*)d_in[15];

  const int N = in_sizes[0] / 128;
  const int E = in_sizes[1];
  const int G = out_size / 128;
  const int L = in_sizes[6] / (128*128);

  float* bufA   = (float*)d_ws;
  float* bufB   = bufA + (size_t)N*128;
  float* sums   = bufB + (size_t)N*128;
  float* counts = sums + (size_t)G*128;

  // h = LN(h_in)
  input_ln_k<<<(N+3)/4, 256, 0, stream>>>(h_in, ilng, ilnb, bufA, N);

  float* hcur = bufA;
  float* tmp  = bufB;
  const int gblocks = (N + 127)/128;
  const int sblocks = (int)(((long)E*128 + 255)/256);

  for (int i=0;i<L;i++){
    hipMemsetAsync(tmp, 0, (size_t)N*128*sizeof(float), stream);
    scatter_edges<<<sblocks, 256, 0, stream>>>(hcur, src, dst, tmp, E);
    gemm_fused<0><<<gblocks, 256, 0, stream>>>(
        hcur, tmp, W1 + (size_t)i*128*128, b1 + i*128,
        ln1g + i*128, ln1b + i*128, nullptr, nullptr, nullptr, tmp, N);
    gemm_fused<1><<<gblocks, 256, 0, stream>>>(
        tmp, nullptr, W2 + (size_t)i*128*128, b2 + i*128,
        ln2g + i*128, ln2b + i*128, ng + i*128, nb + i*128,
        (i>0) ? hcur : nullptr, tmp, N);
    float* t2 = hcur; hcur = tmp; tmp = t2;
  }

  // pooling
  hipMemsetAsync(sums, 0, ((size_t)G*128 + G)*sizeof(float), stream);
  int pw = (N + 255)/256;               // waves
  int pblocks = (pw + 3)/4;
  pool_k<<<pblocks, 256, 0, stream>>>(hcur, gids, sums, counts, N);
  norm_k<<<(G*128 + 255)/256, 256, 0, stream>>>(sums, counts, (float*)d_out, G*128);
}